// Round 22
// baseline (467.360 us; speedup 1.0000x reference)
//
#include <hip/hip_runtime.h>

// SIREN MLP fused kernel, MI355X gfx950 — round 22 (k-outer W-streaming, 8 waves/SIMD).
// [262144,3] -> sin(30(xW^T+b)) -> 4x sin(30(hW^T+b)) [256x256] -> linear -> [262144,3]
// All global tensors fp32. h kept as fp16 (MFMA operand), fp32 accumulate.
// R22 tests the LAST untried design cell: trade W-in-AGPR residency for occupancy.
//   Session model: W-resident waves need ~124 regs -> hard 4 waves/SIMD; all
//   occupancy attempts failed (R6 starve, R12 spill, R13 LDS-moot).
//   k-OUTER loop: per k-chunk load 2 transient W frags (8 regs) + 2 bh frags,
//   feed acc[m2][np] (16 regs) held across k. Live ~55-60 <= the 64-reg /
//   8-wave budget (launch_bounds(512,8); demand<=budget, unlike R6).
//   BM=32, LDS ~39.4 KB (first-layer table overlaid on hbuf[1], dead after L1)
//   -> 4 blocks/CU x 8 waves = 32 waves/CU. W L2 traffic 2x/point (~20 TB/s
//   aggregate, 57% of ceiling). Per-output accumulation order UNCHANGED ->
//   absmax must be bit-exact 0.0009765625.
// Tripwires: VGPR<=64 & Occupancy>=80 (mechanism); FETCH ~3.7MB (no spill).

typedef _Float16 hf8 __attribute__((ext_vector_type(8)));
typedef _Float16 hf4 __attribute__((ext_vector_type(4)));
typedef _Float16 hf2 __attribute__((ext_vector_type(2)));
typedef __fp16   fp16x2 __attribute__((ext_vector_type(2)));   // cvt_pkrtz return type
typedef float floatx4 __attribute__((ext_vector_type(4)));

#define HID 256
#define NHID 4
#define BM 32           // points per block
#define STRIDE 264      // padded LDS row stride (elems): 528B = 4 dwords mod 32 banks
#define THREADS 512     // 8 waves; wave w owns output features [32w, 32w+32)
#define C_REV 4.774648292756860f   // 30 / (2*pi)
#define WH_ELEMS (NHID*HID*HID)    // 262144
#define WS_HALVES (WH_ELEMS + 3*HID)

// sin(2*pi*r): v_fract -> [0,1) (sin periodic; fract output always in HW range)
__device__ __forceinline__ float sin_rev(float r){
  float f, s;
  asm("v_fract_f32 %0, %1" : "=v"(f) : "v"(r));
  asm("v_sin_f32 %0, %1"   : "=v"(s) : "v"(f));
  return s;
}
__device__ __forceinline__ hf2 pk2(float a, float b){
  const fp16x2 p = __builtin_amdgcn_cvt_pkrtz(a, b);
  return __builtin_bit_cast(hf2, p);
}
__device__ __forceinline__ hf8 ld8h_f32(const float* f){
  const floatx4 a = *(const floatx4*)f;
  const floatx4 b = *(const floatx4*)(f + 4);
  hf8 o;
#pragma unroll
  for (int e = 0; e < 4; ++e){ o[e] = (_Float16)a[e]; o[4+e] = (_Float16)b[e]; }
  return o;
}
__device__ __forceinline__ int hix(int r, int c){ return r*STRIDE + c; }

// ---- prepass: w_hidden, w_final fp32 -> fp16 in ws (unscaled) ----
__global__ void prep_kernel(const float* __restrict__ wh,
                            const float* __restrict__ wfin,
                            _Float16* __restrict__ ws){
  const int i = blockIdx.x*256 + threadIdx.x;
  if (i < WH_ELEMS)            ws[i] = (_Float16)wh[i];
  else if (i < WS_HALVES)      ws[i] = (_Float16)wfin[i - WH_ELEMS];
}

template<bool WS>
__global__ __launch_bounds__(THREADS, 8) void siren_kernel(
    const float* __restrict__ x, const float* __restrict__ w_first,
    const float* __restrict__ b_first, const float* __restrict__ w_hidden,
    const float* __restrict__ b_hidden, const float* __restrict__ w_final,
    const float* __restrict__ b_final, const _Float16* __restrict__ wsh,
    float* __restrict__ out)
{
  __shared__ __align__(16) _Float16 hbuf[2][BM*STRIDE];  // 33 KB double-buffered h (padded rows)
  __shared__ __align__(16) float    blds[NHID*HID];      // 4 KB hidden biases * C_REV
  __shared__ __align__(16) _Float16 wflds[3*HID];        // 1.5 KB final-layer weights fp16
  // first-layer table overlaid on hbuf[1] (4 KB; dead once L0 writes hbuf[1])
  float* wf = (float*)&hbuf[1][0];

  const int tid = threadIdx.x;
  const int blk = blockIdx.x;

  const int wv  = tid >> 6;
  const int l   = tid & 63;
  const int l15 = l & 15;
  const int l4  = l >> 4;

  if (tid < HID){
    wf[tid*4+0] = w_first[tid*3+0] * C_REV;
    wf[tid*4+1] = w_first[tid*3+1] * C_REV;
    wf[tid*4+2] = w_first[tid*3+2] * C_REV;
    wf[tid*4+3] = b_first[tid]     * C_REV;
  }
#pragma unroll
  for (int i = tid; i < NHID*HID; i += THREADS)
    blds[i] = b_hidden[i] * C_REV;
#pragma unroll
  for (int i = tid; i < 3*HID; i += THREADS)
    wflds[i] = WS ? wsh[WH_ELEMS + i] : (_Float16)w_final[i];
  __syncthreads();

  // ---- first layer (K=3, VALU): 32 rows x 16 col-strips of 16 ----
  {
    const int row = tid & (BM-1);
    const int cb  = (tid >> 5) * 16;
    const int gr  = blk*BM + row;
    const float x0 = x[gr*3+0];
    const float x1 = x[gr*3+1];
    const float x2 = x[gr*3+2];
#pragma unroll
    for (int g = 0; g < 2; ++g){
      float sv[8];
#pragma unroll
      for (int e = 0; e < 8; ++e){
        const int j = cb + g*8 + e;
        const floatx4 w = *(const floatx4*)(&wf[j*4]);   // wave-uniform broadcast
        float r = w[3];
        r = fmaf(x0, w[0], r);
        r = fmaf(x1, w[1], r);
        r = fmaf(x2, w[2], r);
        sv[e] = sin_rev(r);
      }
      hf8 hv;
#pragma unroll
      for (int p = 0; p < 4; ++p){
        const hf2 pk = pk2(sv[2*p], sv[2*p+1]);
        hv[2*p] = pk[0]; hv[2*p+1] = pk[1];
      }
      *(hf8*)(&hbuf[0][hix(row, cb + g*8)]) = hv;
    }
  }
  __syncthreads();

  // ---- hidden layers, k-OUTER: stream W, hold acc[m2][np] ----
  // A = W rows (m=l&15, k-chunk=(l>>4)*8); B = h^T from LDS (same k map ->
  // k-permutation cancels). D: reg g -> feature (l>>4)*4+g, col -> point l&15.
  // Last layer: epilogue computes final-linear partials (fred overlays hbuf[0],
  // which holds L1's output, dead after L2 reads it).
  float* fred = (float*)&hbuf[0][0];

  const _Float16* rb = &hbuf[0][0];
  _Float16*       wb = &hbuf[1][0];
#pragma unroll 1
  for (int L = 0; L < NHID; ++L){
    const bool last = (L == NHID-1);
    float bC[2][4];
#pragma unroll
    for (int m2 = 0; m2 < 2; ++m2){
      const floatx4 bb = *(const floatx4*)(&blds[L*HID + wv*32 + m2*16 + l4*4]);
#pragma unroll
      for (int g = 0; g < 4; ++g) bC[m2][g] = bb[g];
    }

    floatx4 a00 = {0.f,0.f,0.f,0.f};   // [m2=0][np=0]
    floatx4 a10 = {0.f,0.f,0.f,0.f};   // [m2=1][np=0]
    floatx4 a01 = {0.f,0.f,0.f,0.f};   // [m2=0][np=1]
    floatx4 a11 = {0.f,0.f,0.f,0.f};   // [m2=1][np=1]

    const _Float16* wp0h = wsh + L*HID*HID + (wv*32 + l15)*HID + l4*8;
    const float*    wp0f = w_hidden + L*HID*HID + (wv*32 + l15)*HID + l4*8;
#pragma unroll
    for (int k = 0; k < 8; ++k){
      hf8 w0, w1;
      if (WS){
        w0 = *(const hf8*)(wp0h + k*32);            // one dwordx4
        w1 = *(const hf8*)(wp0h + 16*HID + k*32);
      } else {
        w0 = ld8h_f32(wp0f + k*32);
        w1 = ld8h_f32(wp0f + 16*HID + k*32);
      }
      const hf8 b0 = *(const hf8*)(rb + hix(l15,      k*32 + l4*8));   // np=0 rows
      const hf8 b1 = *(const hf8*)(rb + hix(16 + l15, k*32 + l4*8));   // np=1 rows
      a00 = __builtin_amdgcn_mfma_f32_16x16x32_f16(w0, b0, a00, 0, 0, 0);
      a10 = __builtin_amdgcn_mfma_f32_16x16x32_f16(w1, b0, a10, 0, 0, 0);
      a01 = __builtin_amdgcn_mfma_f32_16x16x32_f16(w0, b1, a01, 0, 0, 0);
      a11 = __builtin_amdgcn_mfma_f32_16x16x32_f16(w1, b1, a11, 0, 0, 0);
    }

    // ---- epilogue: np x m2 ----
#pragma unroll
    for (int np = 0; np < 2; ++np){
      const int r = np*16 + l15;
      float p0 = 0.f, p1 = 0.f, p2 = 0.f;
#pragma unroll
      for (int m2 = 0; m2 < 2; ++m2){
        const floatx4 z = np ? (m2 ? a11 : a01) : (m2 ? a10 : a00);
        float sv[4];
#pragma unroll
        for (int g = 0; g < 4; ++g)
          sv[g] = sin_rev(fmaf(z[g], C_REV, bC[m2][g]));
        const int jb = wv*32 + m2*16 + l4*4;
        if (!last){
          const hf2 q0 = pk2(sv[0], sv[1]);
          const hf2 q1 = pk2(sv[2], sv[3]);
          hf4 hv; hv[0]=q0[0]; hv[1]=q0[1]; hv[2]=q1[0]; hv[3]=q1[1];
          *(hf4*)(wb + hix(r, jb)) = hv;
        } else {
          const hf4 w0 = *(const hf4*)(&wflds[0*HID + jb]);
          const hf4 w1 = *(const hf4*)(&wflds[1*HID + jb]);
          const hf4 w2 = *(const hf4*)(&wflds[2*HID + jb]);
#pragma unroll
          for (int g = 0; g < 4; ++g){
            p0 = fmaf(sv[g], (float)w0[g], p0);
            p1 = fmaf(sv[g], (float)w1[g], p1);
            p2 = fmaf(sv[g], (float)w2[g], p2);
          }
        }
      }
      if (last){
        // reduce over l4 (bits 4,5 of lane): 4 lanes share point r
        p0 += __shfl_xor(p0, 16); p0 += __shfl_xor(p0, 32);
        p1 += __shfl_xor(p1, 16); p1 += __shfl_xor(p1, 32);
        p2 += __shfl_xor(p2, 16); p2 += __shfl_xor(p2, 32);
        if (l < 16){
          floatx4 pv = {p0, p1, p2, 0.f};
          *(floatx4*)(&fred[(wv*BM + r)*4]) = pv;   // 16B/lane consecutive: conflict-free
        }
      }
    }
    _Float16* t = (_Float16*)rb; rb = wb; wb = t;
    __syncthreads();
  }

  // ---- mini-reduce: sum 8 wave partials + bias -> out ----
  if (tid < BM*4){
    const int pt = tid >> 2;
    const int o  = tid & 3;
    if (o < 3){
      float s = 0.f;
#pragma unroll
      for (int w = 0; w < 8; ++w)
        s += fred[(w*BM + pt)*4 + o];
      out[(blk*BM + pt)*3 + o] = s + b_final[o];
    }
  }
}

extern "C" void kernel_launch(void* const* d_in, const int* in_sizes, int n_in,
                              void* d_out, int out_size, void* d_ws, size_t ws_size,
                              hipStream_t stream) {
  const float* x        = (const float*)d_in[0];
  const float* w_first  = (const float*)d_in[1];
  const float* b_first  = (const float*)d_in[2];
  const float* w_hidden = (const float*)d_in[3];
  const float* b_hidden = (const float*)d_in[4];
  const float* w_final  = (const float*)d_in[5];
  const float* b_final  = (const float*)d_in[6];
  float* out = (float*)d_out;
  _Float16* wsh = (_Float16*)d_ws;

  const int npts = in_sizes[0] / 3;
  const int grid = npts / BM;   // 8192
  const bool use_ws = (ws_size >= (size_t)WS_HALVES * sizeof(_Float16));

  if (use_ws){
    const int pgrid = (WS_HALVES + 255) / 256;
    hipLaunchKernelGGL(prep_kernel, dim3(pgrid), dim3(256), 0, stream,
                       w_hidden, w_final, wsh);
    hipLaunchKernelGGL(siren_kernel<true>, dim3(grid), dim3(THREADS), 0, stream,
                       x, w_first, b_first, w_hidden, b_hidden, w_final, b_final,
                       wsh, out);
  } else {
    hipLaunchKernelGGL(siren_kernel<false>, dim3(grid), dim3(THREADS), 0, stream,
                       x, w_first, b_first, w_hidden, b_hidden, w_final, b_final,
                       wsh, out);
  }
}

// Round 23
// 257.522 us; speedup vs baseline: 1.8148x; 1.8148x over previous
//
#include <hip/hip_runtime.h>

// SIREN MLP fused kernel, MI355X gfx950 — FINAL (= round 19, session best 257.7us).
// [262144,3] -> sin(30(xW^T+b)) -> 4x sin(30(hW^T+b)) [256x256] -> linear -> [262144,3]
// All global tensors fp32. h kept as fp16 (MFMA operand), fp32 accumulate.
//
// Session conclusion (22 rounds): the register allocator offers exactly one
// viable operating point for this computation — ~124 total regs/wave (60 VGPR
// + 64 AGPR W-fragments) at 4 waves/SIMD. Demanding 8 waves/EU squeezes VGPR
// to 32 (starvation: R6 W-resident 527us, R22 k-outer 467us); exceeding 128
// regs spills to scratch (R12: 2.4GB HBM round-trip, 1145us); LDS size is
// irrelevant to occupancy (R13). At the viable point, all pipes sit <31% and
// the residual is dependency latency; every schedule lever was isolated:
// kept -> padded LDS rows (bank-conflict-minimal, affine offsets), W/bias
// cross-layer software pipeline, bias/final-W LDS tables, np rotation,
// unroll 2, fract+sin epilogue, cvt_pkrtz packing, fused final layer;
// refuted -> setprio (R18: removal helps), k-split acc chains (R17),
// persistent blocks (R20: L2 write-thrash), bigger/smaller tiles (R13/R15),
// bias-as-MFMA-C (R10: wrong C layout assumption).

typedef _Float16 hf8 __attribute__((ext_vector_type(8)));
typedef _Float16 hf4 __attribute__((ext_vector_type(4)));
typedef _Float16 hf2 __attribute__((ext_vector_type(2)));
typedef __fp16   fp16x2 __attribute__((ext_vector_type(2)));   // cvt_pkrtz return type
typedef float floatx4 __attribute__((ext_vector_type(4)));

#define HID 256
#define NHID 4
#define BM 64           // points per block
#define STRIDE 264      // padded LDS row stride (elems): 528B = 4 dwords mod 32 banks
#define THREADS 512     // 8 waves; wave w owns output features [32w, 32w+32)
#define NP (BM/16)      // 4 point-tiles per wave
#define C_REV 4.774648292756860f   // 30 / (2*pi)
#define WH_ELEMS (NHID*HID*HID)    // 262144
#define WS_HALVES (WH_ELEMS + 3*HID)

// sin(2*pi*r): v_fract -> [0,1) (sin periodic; fract output always in HW range)
__device__ __forceinline__ float sin_rev(float r){
  float f, s;
  asm("v_fract_f32 %0, %1" : "=v"(f) : "v"(r));
  asm("v_sin_f32 %0, %1"   : "=v"(s) : "v"(f));
  return s;
}
__device__ __forceinline__ hf2 pk2(float a, float b){
  const fp16x2 p = __builtin_amdgcn_cvt_pkrtz(a, b);
  return __builtin_bit_cast(hf2, p);
}
__device__ __forceinline__ hf8 ld8h_f32(const float* f){
  const floatx4 a = *(const floatx4*)f;
  const floatx4 b = *(const floatx4*)(f + 4);
  hf8 o;
#pragma unroll
  for (int e = 0; e < 4; ++e){ o[e] = (_Float16)a[e]; o[4+e] = (_Float16)b[e]; }
  return o;
}
__device__ __forceinline__ int hix(int r, int c){ return r*STRIDE + c; }

// ---- prepass: w_hidden, w_final fp32 -> fp16 in ws (unscaled) ----
__global__ void prep_kernel(const float* __restrict__ wh,
                            const float* __restrict__ wfin,
                            _Float16* __restrict__ ws){
  const int i = blockIdx.x*256 + threadIdx.x;
  if (i < WH_ELEMS)            ws[i] = (_Float16)wh[i];
  else if (i < WS_HALVES)      ws[i] = (_Float16)wfin[i - WH_ELEMS];
}

template<bool WS>
__global__ __launch_bounds__(THREADS, 4) void siren_kernel(
    const float* __restrict__ x, const float* __restrict__ w_first,
    const float* __restrict__ b_first, const float* __restrict__ w_hidden,
    const float* __restrict__ b_hidden, const float* __restrict__ w_final,
    const float* __restrict__ b_final, const _Float16* __restrict__ wsh,
    float* __restrict__ out)
{
  __shared__ __align__(16) _Float16 hbuf[2][BM*STRIDE];  // 66 KB double-buffered h (padded rows)
  __shared__ __align__(16) float    wf[HID*4];           // 4 KB first-layer (w0,w1,w2,b)*C_REV
  __shared__ __align__(16) float    blds[NHID*HID];      // 4 KB hidden biases * C_REV
  __shared__ __align__(16) _Float16 wflds[3*HID];        // 1.5 KB final-layer weights fp16

  const int tid = threadIdx.x;
  const int blk = blockIdx.x;

  const int wv  = tid >> 6;
  const int l   = tid & 63;
  const int l15 = l & 15;
  const int l4  = l >> 4;

  if (tid < HID){
    wf[tid*4+0] = w_first[tid*3+0] * C_REV;
    wf[tid*4+1] = w_first[tid*3+1] * C_REV;
    wf[tid*4+2] = w_first[tid*3+2] * C_REV;
    wf[tid*4+3] = b_first[tid]     * C_REV;
  }
#pragma unroll
  for (int i = tid; i < NHID*HID; i += THREADS)
    blds[i] = b_hidden[i] * C_REV;
#pragma unroll
  for (int i = tid; i < 3*HID; i += THREADS)
    wflds[i] = WS ? wsh[WH_ELEMS + i] : (_Float16)w_final[i];
  __syncthreads();

  // ---- prologue: issue layer-0 W loads (overlap with first-layer VALU) ----
  hf8   wfr[2][8];
  float bC[2][4];
#pragma unroll
  for (int m2 = 0; m2 < 2; ++m2){
    const int jrow  = wv*32 + m2*16 + l15;
    const int wbase = jrow*HID + l4*8;
#pragma unroll
    for (int k = 0; k < 8; ++k){
      if (WS) wfr[m2][k] = *(const hf8*)(wsh + wbase + k*32);
      else    wfr[m2][k] = ld8h_f32(w_hidden + wbase + k*32);
    }
    const int j0 = wv*32 + m2*16 + l4*4;
    const floatx4 bb = *(const floatx4*)(&blds[j0]);
#pragma unroll
    for (int g = 0; g < 4; ++g) bC[m2][g] = bb[g];
  }
  __builtin_amdgcn_sched_barrier(0);   // keep W0 loads above first-layer compute

  // ---- first layer (K=3, VALU): 64 rows x 8 col-strips of 32 ----
  {
    const int row = tid & (BM-1);
    const int cb  = (tid >> 6) * 32;
    const int gr  = blk*BM + row;
    const float x0 = x[gr*3+0];
    const float x1 = x[gr*3+1];
    const float x2 = x[gr*3+2];
#pragma unroll
    for (int g = 0; g < 4; ++g){
      float sv[8];
#pragma unroll
      for (int e = 0; e < 8; ++e){
        const int j = cb + g*8 + e;
        const floatx4 w = *(const floatx4*)(&wf[j*4]);   // wave-uniform broadcast
        float r = w[3];
        r = fmaf(x0, w[0], r);
        r = fmaf(x1, w[1], r);
        r = fmaf(x2, w[2], r);
        sv[e] = sin_rev(r);
      }
      hf8 hv;
#pragma unroll
      for (int p = 0; p < 4; ++p){
        const hf2 pk = pk2(sv[2*p], sv[2*p+1]);
        hv[2*p] = pk[0]; hv[2*p+1] = pk[1];
      }
      *(hf8*)(&hbuf[0][hix(row, cb + g*8)]) = hv;
    }
  }
  __syncthreads();

  // ---- hidden layers: z^T = W.h^T via mfma_f32_16x16x32_f16 ----
  // A = W rows (m=l&15, k-chunk=(l>>4)*8); B = h^T from LDS (same k map ->
  // k-permutation cancels). D: reg g -> feature (l>>4)*4+g, col -> point l&15.
  // Last layer: epilogue computes final-linear partials instead of writing h.
  float* fred = (float*)&hbuf[0][0];

  const _Float16* rb = &hbuf[0][0];
  _Float16*       wb = &hbuf[1][0];
#pragma unroll 1
  for (int L = 0; L < NHID; ++L){
    const bool last = (L == NHID-1);
#pragma unroll 2
    for (int np = 0; np < NP; ++np){
      const int npr = (np + wv) & 3;            // per-wave rotation (tiles independent)
      const int r = npr*16 + l15;
      hf8 bh[8];
#pragma unroll
      for (int k = 0; k < 8; ++k)
        bh[k] = *(const hf8*)(rb + hix(r, k*32 + l4*8));   // affine -> offset imm
      floatx4 acc0 = {0.f,0.f,0.f,0.f};
      floatx4 acc1 = {0.f,0.f,0.f,0.f};
#pragma unroll
      for (int k = 0; k < 8; ++k){
        acc0 = __builtin_amdgcn_mfma_f32_16x16x32_f16(wfr[0][k], bh[k], acc0, 0, 0, 0);
        acc1 = __builtin_amdgcn_mfma_f32_16x16x32_f16(wfr[1][k], bh[k], acc1, 0, 0, 0);
      }
      float p0 = 0.f, p1 = 0.f, p2 = 0.f;
#pragma unroll
      for (int m2 = 0; m2 < 2; ++m2){
        const floatx4 z = m2 ? acc1 : acc0;
        float sv[4];
#pragma unroll
        for (int g = 0; g < 4; ++g)
          sv[g] = sin_rev(fmaf(z[g], C_REV, bC[m2][g]));
        const int jb = wv*32 + m2*16 + l4*4;
        if (!last){
          const hf2 q0 = pk2(sv[0], sv[1]);
          const hf2 q1 = pk2(sv[2], sv[3]);
          hf4 hv; hv[0]=q0[0]; hv[1]=q0[1]; hv[2]=q1[0]; hv[3]=q1[1];
          *(hf4*)(wb + hix(r, jb)) = hv;
        } else {
          const hf4 w0 = *(const hf4*)(&wflds[0*HID + jb]);
          const hf4 w1 = *(const hf4*)(&wflds[1*HID + jb]);
          const hf4 w2 = *(const hf4*)(&wflds[2*HID + jb]);
#pragma unroll
          for (int g = 0; g < 4; ++g){
            p0 = fmaf(sv[g], (float)w0[g], p0);
            p1 = fmaf(sv[g], (float)w1[g], p1);
            p2 = fmaf(sv[g], (float)w2[g], p2);
          }
        }
      }
      if (last){
        // reduce over l4 (bits 4,5 of lane): 4 lanes share point r
        p0 += __shfl_xor(p0, 16); p0 += __shfl_xor(p0, 32);
        p1 += __shfl_xor(p1, 16); p1 += __shfl_xor(p1, 32);
        p2 += __shfl_xor(p2, 16); p2 += __shfl_xor(p2, 32);
        if (l < 16){
          floatx4 pv = {p0, p1, p2, 0.f};
          *(floatx4*)(&fred[(wv*BM + r)*4]) = pv;   // consecutive 16B/lane: conflict-free
        }
      }
    }

    // ---- prefetch next layer's W/bias BEFORE the barrier (vmcnt spans it) ----
    __builtin_amdgcn_sched_barrier(0);   // don't hoist into np loop (liveness)
    if (L + 1 < NHID){
#pragma unroll
      for (int m2 = 0; m2 < 2; ++m2){
        const int jrow  = wv*32 + m2*16 + l15;
        const int wbase = (L+1)*HID*HID + jrow*HID + l4*8;
#pragma unroll
        for (int k = 0; k < 8; ++k){
          if (WS) wfr[m2][k] = *(const hf8*)(wsh + wbase + k*32);
          else    wfr[m2][k] = ld8h_f32(w_hidden + wbase + k*32);
        }
        const int j0 = wv*32 + m2*16 + l4*4;
        const floatx4 bb = *(const floatx4*)(&blds[(L+1)*HID + j0]);
#pragma unroll
        for (int g = 0; g < 4; ++g) bC[m2][g] = bb[g];
      }
    }
    _Float16* t = (_Float16*)rb; rb = wb; wb = t;
    __syncthreads();
  }

  // ---- mini-reduce: sum 8 wave partials + bias -> out ----
  if (tid < BM*4){
    const int pt = tid >> 2;
    const int o  = tid & 3;
    if (o < 3){
      float s = 0.f;
#pragma unroll
      for (int w = 0; w < 8; ++w)
        s += fred[(w*BM + pt)*4 + o];
      out[(blk*BM + pt)*3 + o] = s + b_final[o];
    }
  }
}

extern "C" void kernel_launch(void* const* d_in, const int* in_sizes, int n_in,
                              void* d_out, int out_size, void* d_ws, size_t ws_size,
                              hipStream_t stream) {
  const float* x        = (const float*)d_in[0];
  const float* w_first  = (const float*)d_in[1];
  const float* b_first  = (const float*)d_in[2];
  const float* w_hidden = (const float*)d_in[3];
  const float* b_hidden = (const float*)d_in[4];
  const float* w_final  = (const float*)d_in[5];
  const float* b_final  = (const float*)d_in[6];
  float* out = (float*)d_out;
  _Float16* wsh = (_Float16*)d_ws;

  const int npts = in_sizes[0] / 3;
  const int grid = npts / BM;   // 4096
  const bool use_ws = (ws_size >= (size_t)WS_HALVES * sizeof(_Float16));

  if (use_ws){
    const int pgrid = (WS_HALVES + 255) / 256;
    hipLaunchKernelGGL(prep_kernel, dim3(pgrid), dim3(256), 0, stream,
                       w_hidden, w_final, wsh);
    hipLaunchKernelGGL(siren_kernel<true>, dim3(grid), dim3(THREADS), 0, stream,
                       x, w_first, b_first, w_hidden, b_hidden, w_final, b_final,
                       wsh, out);
  } else {
    hipLaunchKernelGGL(siren_kernel<false>, dim3(grid), dim3(THREADS), 0, stream,
                       x, w_first, b_first, w_hidden, b_hidden, w_final, b_final,
                       wsh, out);
  }
}

// Round 25
// 257.430 us; speedup vs baseline: 1.8155x; 1.0004x over previous
//
#include <hip/hip_runtime.h>

// SIREN MLP fused kernel, MI355X gfx950 — FINAL (= round 19; 257.5-257.9us,
// verified stable across three independent full harness runs incl. post-timing
// re-validation: R19, R21, R23).
// [262144,3] -> sin(30(xW^T+b)) -> 4x sin(30(hW^T+b)) [256x256] -> linear -> [262144,3]
// All global tensors fp32. h kept as fp16 (MFMA operand), fp32 accumulate.
//
// Session conclusion (24 rounds): the register allocator offers exactly one
// viable operating point — ~124 total regs/wave (60 VGPR + 64 AGPR W-frags)
// at 4 waves/SIMD. Demanding 8 waves/EU squeezes VGPR to 32 (starvation:
// R6 527us, R22/R24 467us + R24 post-timing race in the overlay variant);
// >128 regs spills to scratch (R12: 1145us); LDS is not the occupancy binder
// (R13); persistent blocks thrash L2 writes (R20). At the viable point all
// pipes sit <31% (latency plateau, not HW roofline); every schedule lever
// isolated: kept -> padded LDS rows, cross-layer W/bias software pipeline,
// bias/final-W LDS tables, np rotation, unroll 2, fract+sin epilogue,
// cvt_pkrtz packing, fused final layer; refuted -> setprio (R18), k-split
// acc chains (R17), bias-as-MFMA-C (R10), tile scaling both ways (R13/R15).

typedef _Float16 hf8 __attribute__((ext_vector_type(8)));
typedef _Float16 hf4 __attribute__((ext_vector_type(4)));
typedef _Float16 hf2 __attribute__((ext_vector_type(2)));
typedef __fp16   fp16x2 __attribute__((ext_vector_type(2)));   // cvt_pkrtz return type
typedef float floatx4 __attribute__((ext_vector_type(4)));

#define HID 256
#define NHID 4
#define BM 64           // points per block
#define STRIDE 264      // padded LDS row stride (elems): 528B = 4 dwords mod 32 banks
#define THREADS 512     // 8 waves; wave w owns output features [32w, 32w+32)
#define NP (BM/16)      // 4 point-tiles per wave
#define C_REV 4.774648292756860f   // 30 / (2*pi)
#define WH_ELEMS (NHID*HID*HID)    // 262144
#define WS_HALVES (WH_ELEMS + 3*HID)

// sin(2*pi*r): v_fract -> [0,1) (sin periodic; fract output always in HW range)
__device__ __forceinline__ float sin_rev(float r){
  float f, s;
  asm("v_fract_f32 %0, %1" : "=v"(f) : "v"(r));
  asm("v_sin_f32 %0, %1"   : "=v"(s) : "v"(f));
  return s;
}
__device__ __forceinline__ hf2 pk2(float a, float b){
  const fp16x2 p = __builtin_amdgcn_cvt_pkrtz(a, b);
  return __builtin_bit_cast(hf2, p);
}
__device__ __forceinline__ hf8 ld8h_f32(const float* f){
  const floatx4 a = *(const floatx4*)f;
  const floatx4 b = *(const floatx4*)(f + 4);
  hf8 o;
#pragma unroll
  for (int e = 0; e < 4; ++e){ o[e] = (_Float16)a[e]; o[4+e] = (_Float16)b[e]; }
  return o;
}
__device__ __forceinline__ int hix(int r, int c){ return r*STRIDE + c; }

// ---- prepass: w_hidden, w_final fp32 -> fp16 in ws (unscaled) ----
__global__ void prep_kernel(const float* __restrict__ wh,
                            const float* __restrict__ wfin,
                            _Float16* __restrict__ ws){
  const int i = blockIdx.x*256 + threadIdx.x;
  if (i < WH_ELEMS)            ws[i] = (_Float16)wh[i];
  else if (i < WS_HALVES)      ws[i] = (_Float16)wfin[i - WH_ELEMS];
}

template<bool WS>
__global__ __launch_bounds__(THREADS, 4) void siren_kernel(
    const float* __restrict__ x, const float* __restrict__ w_first,
    const float* __restrict__ b_first, const float* __restrict__ w_hidden,
    const float* __restrict__ b_hidden, const float* __restrict__ w_final,
    const float* __restrict__ b_final, const _Float16* __restrict__ wsh,
    float* __restrict__ out)
{
  __shared__ __align__(16) _Float16 hbuf[2][BM*STRIDE];  // 66 KB double-buffered h (padded rows)
  __shared__ __align__(16) float    wf[HID*4];           // 4 KB first-layer (w0,w1,w2,b)*C_REV
  __shared__ __align__(16) float    blds[NHID*HID];      // 4 KB hidden biases * C_REV
  __shared__ __align__(16) _Float16 wflds[3*HID];        // 1.5 KB final-layer weights fp16

  const int tid = threadIdx.x;
  const int blk = blockIdx.x;

  const int wv  = tid >> 6;
  const int l   = tid & 63;
  const int l15 = l & 15;
  const int l4  = l >> 4;

  if (tid < HID){
    wf[tid*4+0] = w_first[tid*3+0] * C_REV;
    wf[tid*4+1] = w_first[tid*3+1] * C_REV;
    wf[tid*4+2] = w_first[tid*3+2] * C_REV;
    wf[tid*4+3] = b_first[tid]     * C_REV;
  }
#pragma unroll
  for (int i = tid; i < NHID*HID; i += THREADS)
    blds[i] = b_hidden[i] * C_REV;
#pragma unroll
  for (int i = tid; i < 3*HID; i += THREADS)
    wflds[i] = WS ? wsh[WH_ELEMS + i] : (_Float16)w_final[i];
  __syncthreads();

  // ---- prologue: issue layer-0 W loads (overlap with first-layer VALU) ----
  hf8   wfr[2][8];
  float bC[2][4];
#pragma unroll
  for (int m2 = 0; m2 < 2; ++m2){
    const int jrow  = wv*32 + m2*16 + l15;
    const int wbase = jrow*HID + l4*8;
#pragma unroll
    for (int k = 0; k < 8; ++k){
      if (WS) wfr[m2][k] = *(const hf8*)(wsh + wbase + k*32);
      else    wfr[m2][k] = ld8h_f32(w_hidden + wbase + k*32);
    }
    const int j0 = wv*32 + m2*16 + l4*4;
    const floatx4 bb = *(const floatx4*)(&blds[j0]);
#pragma unroll
    for (int g = 0; g < 4; ++g) bC[m2][g] = bb[g];
  }
  __builtin_amdgcn_sched_barrier(0);   // keep W0 loads above first-layer compute

  // ---- first layer (K=3, VALU): 64 rows x 8 col-strips of 32 ----
  {
    const int row = tid & (BM-1);
    const int cb  = (tid >> 6) * 32;
    const int gr  = blk*BM + row;
    const float x0 = x[gr*3+0];
    const float x1 = x[gr*3+1];
    const float x2 = x[gr*3+2];
#pragma unroll
    for (int g = 0; g < 4; ++g){
      float sv[8];
#pragma unroll
      for (int e = 0; e < 8; ++e){
        const int j = cb + g*8 + e;
        const floatx4 w = *(const floatx4*)(&wf[j*4]);   // wave-uniform broadcast
        float r = w[3];
        r = fmaf(x0, w[0], r);
        r = fmaf(x1, w[1], r);
        r = fmaf(x2, w[2], r);
        sv[e] = sin_rev(r);
      }
      hf8 hv;
#pragma unroll
      for (int p = 0; p < 4; ++p){
        const hf2 pk = pk2(sv[2*p], sv[2*p+1]);
        hv[2*p] = pk[0]; hv[2*p+1] = pk[1];
      }
      *(hf8*)(&hbuf[0][hix(row, cb + g*8)]) = hv;
    }
  }
  __syncthreads();

  // ---- hidden layers: z^T = W.h^T via mfma_f32_16x16x32_f16 ----
  // A = W rows (m=l&15, k-chunk=(l>>4)*8); B = h^T from LDS (same k map ->
  // k-permutation cancels). D: reg g -> feature (l>>4)*4+g, col -> point l&15.
  // Last layer: epilogue computes final-linear partials instead of writing h.
  float* fred = (float*)&hbuf[0][0];

  const _Float16* rb = &hbuf[0][0];
  _Float16*       wb = &hbuf[1][0];
#pragma unroll 1
  for (int L = 0; L < NHID; ++L){
    const bool last = (L == NHID-1);
#pragma unroll 2
    for (int np = 0; np < NP; ++np){
      const int npr = (np + wv) & 3;            // per-wave rotation (tiles independent)
      const int r = npr*16 + l15;
      hf8 bh[8];
#pragma unroll
      for (int k = 0; k < 8; ++k)
        bh[k] = *(const hf8*)(rb + hix(r, k*32 + l4*8));   // affine -> offset imm
      floatx4 acc0 = {0.f,0.f,0.f,0.f};
      floatx4 acc1 = {0.f,0.f,0.f,0.f};
#pragma unroll
      for (int k = 0; k < 8; ++k){
        acc0 = __builtin_amdgcn_mfma_f32_16x16x32_f16(wfr[0][k], bh[k], acc0, 0, 0, 0);
        acc1 = __builtin_amdgcn_mfma_f32_16x16x32_f16(wfr[1][k], bh[k], acc1, 0, 0, 0);
      }
      float p0 = 0.f, p1 = 0.f, p2 = 0.f;
#pragma unroll
      for (int m2 = 0; m2 < 2; ++m2){
        const floatx4 z = m2 ? acc1 : acc0;
        float sv[4];
#pragma unroll
        for (int g = 0; g < 4; ++g)
          sv[g] = sin_rev(fmaf(z[g], C_REV, bC[m2][g]));
        const int jb = wv*32 + m2*16 + l4*4;
        if (!last){
          const hf2 q0 = pk2(sv[0], sv[1]);
          const hf2 q1 = pk2(sv[2], sv[3]);
          hf4 hv; hv[0]=q0[0]; hv[1]=q0[1]; hv[2]=q1[0]; hv[3]=q1[1];
          *(hf4*)(wb + hix(r, jb)) = hv;
        } else {
          const hf4 w0 = *(const hf4*)(&wflds[0*HID + jb]);
          const hf4 w1 = *(const hf4*)(&wflds[1*HID + jb]);
          const hf4 w2 = *(const hf4*)(&wflds[2*HID + jb]);
#pragma unroll
          for (int g = 0; g < 4; ++g){
            p0 = fmaf(sv[g], (float)w0[g], p0);
            p1 = fmaf(sv[g], (float)w1[g], p1);
            p2 = fmaf(sv[g], (float)w2[g], p2);
          }
        }
      }
      if (last){
        // reduce over l4 (bits 4,5 of lane): 4 lanes share point r
        p0 += __shfl_xor(p0, 16); p0 += __shfl_xor(p0, 32);
        p1 += __shfl_xor(p1, 16); p1 += __shfl_xor(p1, 32);
        p2 += __shfl_xor(p2, 16); p2 += __shfl_xor(p2, 32);
        if (l < 16){
          floatx4 pv = {p0, p1, p2, 0.f};
          *(floatx4*)(&fred[(wv*BM + r)*4]) = pv;   // consecutive 16B/lane: conflict-free
        }
      }
    }

    // ---- prefetch next layer's W/bias BEFORE the barrier (vmcnt spans it) ----
    __builtin_amdgcn_sched_barrier(0);   // don't hoist into np loop (liveness)
    if (L + 1 < NHID){
#pragma unroll
      for (int m2 = 0; m2 < 2; ++m2){
        const int jrow  = wv*32 + m2*16 + l15;
        const int wbase = (L+1)*HID*HID + jrow*HID + l4*8;
#pragma unroll
        for (int k = 0; k < 8; ++k){
          if (WS) wfr[m2][k] = *(const hf8*)(wsh + wbase + k*32);
          else    wfr[m2][k] = ld8h_f32(w_hidden + wbase + k*32);
        }
        const int j0 = wv*32 + m2*16 + l4*4;
        const floatx4 bb = *(const floatx4*)(&blds[(L+1)*HID + j0]);
#pragma unroll
        for (int g = 0; g < 4; ++g) bC[m2][g] = bb[g];
      }
    }
    _Float16* t = (_Float16*)rb; rb = wb; wb = t;
    __syncthreads();
  }

  // ---- mini-reduce: sum 8 wave partials + bias -> out ----
  if (tid < BM*4){
    const int pt = tid >> 2;
    const int o  = tid & 3;
    if (o < 3){
      float s = 0.f;
#pragma unroll
      for (int w = 0; w < 8; ++w)
        s += fred[(w*BM + pt)*4 + o];
      out[(blk*BM + pt)*3 + o] = s + b_final[o];
    }
  }
}

extern "C" void kernel_launch(void* const* d_in, const int* in_sizes, int n_in,
                              void* d_out, int out_size, void* d_ws, size_t ws_size,
                              hipStream_t stream) {
  const float* x        = (const float*)d_in[0];
  const float* w_first  = (const float*)d_in[1];
  const float* b_first  = (const float*)d_in[2];
  const float* w_hidden = (const float*)d_in[3];
  const float* b_hidden = (const float*)d_in[4];
  const float* w_final  = (const float*)d_in[5];
  const float* b_final  = (const float*)d_in[6];
  float* out = (float*)d_out;
  _Float16* wsh = (_Float16*)d_ws;

  const int npts = in_sizes[0] / 3;
  const int grid = npts / BM;   // 4096
  const bool use_ws = (ws_size >= (size_t)WS_HALVES * sizeof(_Float16));

  if (use_ws){
    const int pgrid = (WS_HALVES + 255) / 256;
    hipLaunchKernelGGL(prep_kernel, dim3(pgrid), dim3(256), 0, stream,
                       w_hidden, w_final, wsh);
    hipLaunchKernelGGL(siren_kernel<true>, dim3(grid), dim3(THREADS), 0, stream,
                       x, w_first, b_first, w_hidden, b_hidden, w_final, b_final,
                       wsh, out);
  } else {
    hipLaunchKernelGGL(siren_kernel<false>, dim3(grid), dim3(THREADS), 0, stream,
                       x, w_first, b_first, w_hidden, b_hidden, w_final, b_final,
                       wsh, out);
  }
}